// Round 1
// baseline (180.653 us; speedup 1.0000x reference)
//
#include <hip/hip_runtime.h>
#include <math.h>

#define Bq 16
#define Tq 81
#define Dq 128
#define Hq 8
#define BT (Bq*Tq)          // 1296
#define BTD (Bq*Tq*Dq)      // 165888 (out region 0)
// ws layout (floats). P FIRST so K3's small s_load overrun lands in Q (finite).
#define P_SZ   (Bq*Hq*Tq*Tq)        // 839808
#define QV_SZ  (BT*Hq*Dq)           // 1327104
#define P_OFF  0
#define Q_OFF  (P_OFF + P_SZ)
#define V_OFF  (Q_OFF + QV_SZ)
#define WT_OFF (V_OFF + QV_SZ)      // Wt[128][2048]
#define WT_SZ  (2048*128)
#define FWT_OFF (WT_OFF + WT_SZ)    // fwT[128][128]
#define FWT_SZ  (128*128)

__device__ __forceinline__ void fma4(float4& a, float s, const float4 v) {
    a.x = fmaf(s, v.x, a.x); a.y = fmaf(s, v.y, a.y);
    a.z = fmaf(s, v.z, a.z); a.w = fmaf(s, v.w, a.w);
}
__device__ __forceinline__ float l1_4(const float4 q, const float4 k) {
    return fabsf(q.x - k.x) + fabsf(q.y - k.y) + fabsf(q.z - k.z) + fabsf(q.w - k.w);
}
__device__ __forceinline__ int imin(int a, int b) { return a < b ? a : b; }

// ---------------------------------------------------------------------------
// K0: transpose wqkv_w (2048x128 -> Wt 128x2048) and fanout_w (128x128 -> fwT)
// grid (68,4) block 256. bx<64 -> wqkv tiles, else fanout tiles.
// ---------------------------------------------------------------------------
__global__ __launch_bounds__(256) void k_transpose(
    const float* __restrict__ w, const float* __restrict__ fw,
    float* __restrict__ wt, float* __restrict__ fwt)
{
    __shared__ float tile[32][33];
    const int bx = blockIdx.x, by = blockIdx.y;
    const float* src; float* dst; int N, n0;
    if (bx < 64) { src = w;  dst = wt;  N = 2048; n0 = bx * 32; }
    else         { src = fw; dst = fwt; N = 128;  n0 = (bx - 64) * 32; }
    const int k0 = by * 32;
    const int tx = threadIdx.x & 31, ty = threadIdx.x >> 5;   // 32 x 8
    #pragma unroll
    for (int i = ty; i < 32; i += 8)
        tile[i][tx] = src[(size_t)(n0 + i) * Dq + k0 + tx];
    __syncthreads();
    #pragma unroll
    for (int i = ty; i < 32; i += 8)
        dst[(size_t)(k0 + i) * N + n0 + tx] = tile[tx][i];
}

// ---------------------------------------------------------------------------
// K1: QKV GEMM. grid (27, 8): 48 rows x (head=by: 128 q cols + 128 v cols).
// 256 thr = 32 ng (4 consecutive n) x 8 tg (6 rows). LDS-free: Wt coalesced,
// x rows broadcast via L1. Thread tile 6t x 8n (q-float4 + v-float4).
// ---------------------------------------------------------------------------
__global__ __launch_bounds__(256) void k_qkv(
    const float* __restrict__ x, const float* __restrict__ Wt,
    const float* __restrict__ bias, const float* __restrict__ he,
    float* __restrict__ Qo, float* __restrict__ Vo)
{
    const int tid = threadIdx.x;
    const int ng = tid & 31, tg = tid >> 5;
    const int row0 = blockIdx.x * 48 + tg * 6;      // exact: 27*48 = 1296
    const int h = blockIdx.y;
    const int nq = h * 256 + ng * 4;                // q col base; v at +128

    float4 acc[6][2];
    const float4 bq = *(const float4*)(bias + nq);
    const float4 bv = *(const float4*)(bias + nq + 128);
    #pragma unroll
    for (int i = 0; i < 6; ++i) { acc[i][0] = bq; acc[i][1] = bv; }

    const float* xb  = x + (size_t)row0 * Dq;
    const float* wt0 = Wt + nq;

    for (int k = 0; k < Dq; k += 4) {
        float4 b4[4][2];
        #pragma unroll
        for (int kk = 0; kk < 4; ++kk) {
            b4[kk][0] = *(const float4*)(wt0 + (size_t)(k + kk) * 2048);
            b4[kk][1] = *(const float4*)(wt0 + (size_t)(k + kk) * 2048 + 128);
        }
        #pragma unroll
        for (int i = 0; i < 6; ++i) {
            const float4 a = *(const float4*)(xb + (size_t)i * Dq + k);
            #pragma unroll
            for (int j = 0; j < 2; ++j) {
                fma4(acc[i][j], a.x, b4[0][j]);
                fma4(acc[i][j], a.y, b4[1][j]);
                fma4(acc[i][j], a.z, b4[2][j]);
                fma4(acc[i][j], a.w, b4[3][j]);
            }
        }
    }
    const float hescale = he[h];
    #pragma unroll
    for (int i = 0; i < 6; ++i) {
        const size_t row = row0 + i;
        float* qdst = Qo + (row * Hq + h) * Dq + ng * 4;
        float* vdst = Vo + (row * Hq + h) * Dq + ng * 4;
        *(float4*)qdst = acc[i][0];
        float4 vs;
        vs.x = acc[i][1].x * hescale; vs.y = acc[i][1].y * hescale;
        vs.z = acc[i][1].z * hescale; vs.w = acc[i][1].w * hescale;
        *(float4*)vdst = vs;
    }
}

// ---------------------------------------------------------------------------
// K2: scores + softmax + P + ap.  grid (2, 8, 16) = (t-half, h, b), block 256.
// 231 active threads: 11 tg (4 t) x 21 sg (4 s). score = -sum|q - x*wk|/sqrt(D)
// P layout [b][h][s][t] (so K3 can s_load 8 contiguous t's).
// ---------------------------------------------------------------------------
__global__ __launch_bounds__(256) void k_scores(
    const float* __restrict__ x, const float* __restrict__ Q,
    const float* __restrict__ wk, const float* __restrict__ msk,
    float* __restrict__ P, float* __restrict__ out)
{
    __shared__ float sc[44 * 84];
    const int tid = threadIdx.x;
    const int th = blockIdx.x, h = blockIdx.y, b = blockIdx.z;
    const int t0g = th * 41;

    if (tid < 231) {
        const int tg = tid / 21, sg = tid % 21;
        const int tb = tg * 4, s0 = sg * 4;
        float4 acc[4];
        #pragma unroll
        for (int i = 0; i < 4; ++i) acc[i] = make_float4(0.f, 0.f, 0.f, 0.f);

        const float4* qp[4];
        const float4* xp[4];
        #pragma unroll
        for (int i = 0; i < 4; ++i) {
            const int t = imin(t0g + tb + i, Tq - 1);
            qp[i] = (const float4*)(Q + ((size_t)(b * Tq + t) * Hq + h) * Dq);
        }
        #pragma unroll
        for (int j = 0; j < 4; ++j) {
            const int s = imin(s0 + j, Tq - 1);
            xp[j] = (const float4*)(x + (size_t)(b * Tq + s) * Dq);
        }
        const float4* wkp = (const float4*)(wk + (size_t)h * Dq);

        for (int k4 = 0; k4 < 32; ++k4) {
            const float4 wv = wkp[k4];
            float4 xk[4];
            #pragma unroll
            for (int j = 0; j < 4; ++j) {
                const float4 xv = xp[j][k4];
                xk[j].x = xv.x * wv.x; xk[j].y = xv.y * wv.y;
                xk[j].z = xv.z * wv.z; xk[j].w = xv.w * wv.w;
            }
            #pragma unroll
            for (int i = 0; i < 4; ++i) {
                const float4 qv = qp[i][k4];
                acc[i].x += l1_4(qv, xk[0]);
                acc[i].y += l1_4(qv, xk[1]);
                acc[i].z += l1_4(qv, xk[2]);
                acc[i].w += l1_4(qv, xk[3]);
            }
        }
        const float ns = -0.08838834764831845f;   // -1/sqrt(128)
        #pragma unroll
        for (int i = 0; i < 4; ++i) {
            sc[(tb + i) * 84 + s0 + 0] = acc[i].x * ns;
            sc[(tb + i) * 84 + s0 + 1] = acc[i].y * ns;
            sc[(tb + i) * 84 + s0 + 2] = acc[i].z * ns;
            sc[(tb + i) * 84 + s0 + 3] = acc[i].w * ns;
        }
    }
    __syncthreads();

    const int nt = th ? 40 : 41;
    if (tid < nt) {
        float* row = &sc[tid * 84];
        const int tg2 = t0g + tid;
        float m = -1e30f;
        for (int s = 0; s < Tq; ++s) m = fmaxf(m, row[s]);
        float sum = 0.f;
        for (int s = 0; s < Tq; ++s) { const float e = __expf(row[s] - m); row[s] = e; sum += e; }
        const float rinv = 1.0f / sum;
        const float* mrow = msk + ((size_t)h * Tq + tg2) * Tq;
        float* prow = P + ((size_t)(b * Hq + h) * Tq) * Tq;   // + s*Tq + t
        float* apb  = out + BTD;
        for (int s = 0; s < Tq; ++s) {
            const float mv = mrow[s];
            const float pm = row[s] * rinv * mv;
            prow[(size_t)s * Tq + tg2] = pm;
            if (b == 0) apb[((size_t)tg2 * Tq + s) * Hq + h] = pm - 1.0f + mv;
        }
    }
}

// ---------------------------------------------------------------------------
// K3: bo einsum + quick-gelu + fanout + residual. grid (11, 16) = (t-chunk, b),
// block 256 = 4 waves. Wave w handles heads {2w, 2w+1}, all s; lanes = d/2.
// P read via wave-uniform scalar loads (8 contiguous t). Reduce in LDS.
// ---------------------------------------------------------------------------
__global__ __launch_bounds__(256) void k_out(
    const float* __restrict__ x, const float* __restrict__ P,
    const float* __restrict__ V, const float* __restrict__ fwT,
    const float* __restrict__ fb, float* __restrict__ out)
{
    __shared__ float bo_part[4][8][128];
    __shared__ float zs[8][128];
    const int tid = threadIdx.x;
    const int tc = blockIdx.x, b = blockIdx.y;
    const int t0 = tc * 8;
    const int wave = __builtin_amdgcn_readfirstlane(tid >> 6);
    const int lane = tid & 63;

    {
        const int d0 = lane * 2;
        float acc0[8], acc1[8];
        #pragma unroll
        for (int i = 0; i < 8; ++i) { acc0[i] = 0.f; acc1[i] = 0.f; }
        #pragma unroll
        for (int hh = 0; hh < 2; ++hh) {
            const int h = wave * 2 + hh;
            const float* prow = P + ((size_t)(b * Hq + h) * Tq) * Tq + t0; // + s*Tq
            const float* vrow = V + ((size_t)(b * Tq) * Hq + h) * Dq + d0; // + s*Hq*Dq
            for (int s = 0; s < Tq; ++s) {
                const float2 vv = *(const float2*)(vrow + (size_t)s * Hq * Dq);
                const float* pv = prow + (size_t)s * Tq;
                #pragma unroll
                for (int i = 0; i < 8; ++i) {
                    const float p = pv[i];
                    acc0[i] = fmaf(p, vv.x, acc0[i]);
                    acc1[i] = fmaf(p, vv.y, acc1[i]);
                }
            }
        }
        #pragma unroll
        for (int i = 0; i < 8; ++i) {
            bo_part[wave][i][d0] = acc0[i];
            bo_part[wave][i][d0 + 1] = acc1[i];
        }
    }
    __syncthreads();

    #pragma unroll
    for (int u = 0; u < 4; ++u) {
        const int vi = tid * 4 + u;
        const int t = vi >> 7, d = vi & 127;
        const float bo = bo_part[0][t][d] + bo_part[1][t][d]
                       + bo_part[2][t][d] + bo_part[3][t][d];
        const float tt = bo + 4.0f;
        const float sg = 1.0f / (1.0f + __expf(-1.702f * tt));
        zs[t][d] = tt * sg - 4.0f;
    }
    __syncthreads();

    {
        const int t = tid >> 5, dg = tid & 31, dout0 = dg * 4;
        float4 a2 = make_float4(0.f, 0.f, 0.f, 0.f);
        for (int k = 0; k < Dq; k += 4) {
            const float4 z4 = *(const float4*)(&zs[t][k]);
            fma4(a2, z4.x, *(const float4*)(fwT + (size_t)(k + 0) * Dq + dout0));
            fma4(a2, z4.y, *(const float4*)(fwT + (size_t)(k + 1) * Dq + dout0));
            fma4(a2, z4.z, *(const float4*)(fwT + (size_t)(k + 2) * Dq + dout0));
            fma4(a2, z4.w, *(const float4*)(fwT + (size_t)(k + 3) * Dq + dout0));
        }
        const int tg2 = t0 + t;
        if (tg2 < Tq) {
            const float4 xb  = *(const float4*)(x + ((size_t)b * Tq + tg2) * Dq + dout0);
            const float4 fb4 = *(const float4*)(fb + dout0);
            float4 o;
            o.x = xb.x + a2.x + fb4.x; o.y = xb.y + a2.y + fb4.y;
            o.z = xb.z + a2.z + fb4.z; o.w = xb.w + a2.w + fb4.w;
            *(float4*)(out + ((size_t)b * Tq + tg2) * Dq + dout0) = o;
        }
    }
}

extern "C" void kernel_launch(void* const* d_in, const int* in_sizes, int n_in,
                              void* d_out, int out_size, void* d_ws, size_t ws_size,
                              hipStream_t stream) {
    const float* x        = (const float*)d_in[0];
    const float* msk      = (const float*)d_in[1];
    const float* wqkv_w   = (const float*)d_in[2];
    const float* wqkv_b   = (const float*)d_in[3];
    const float* wk_w     = (const float*)d_in[4];
    const float* fanout_w = (const float*)d_in[5];
    const float* fanout_b = (const float*)d_in[6];
    const float* he       = (const float*)d_in[7];
    float* out = (float*)d_out;
    float* ws  = (float*)d_ws;

    float* P   = ws + P_OFF;
    float* Q   = ws + Q_OFF;
    float* V   = ws + V_OFF;
    float* Wt  = ws + WT_OFF;
    float* fwT = ws + FWT_OFF;

    k_transpose<<<dim3(68, 4), 256, 0, stream>>>(wqkv_w, fanout_w, Wt, fwT);
    k_qkv<<<dim3(27, 8), 256, 0, stream>>>(x, Wt, wqkv_b, he, Q, V);
    k_scores<<<dim3(2, 8, 16), 256, 0, stream>>>(x, Q, wk_w, msk, P, out);
    k_out<<<dim3(11, 16), 256, 0, stream>>>(x, P, V, fwT, fanout_b, out);
}

// Round 2
// 179.944 us; speedup vs baseline: 1.0039x; 1.0039x over previous
//
#include <hip/hip_runtime.h>
#include <math.h>

#define Bq 16
#define Tq 81
#define Dq 128
#define Hq 8
#define BT (Bq*Tq)          // 1296
#define BTD (Bq*Tq*Dq)      // 165888 (out region 0)
#define PT 84               // padded t-stride of P (16B-aligned float4 rows)
// ws layout (floats)
#define P_SZ   (Bq*Hq*Tq*PT)        // 870912
#define QV_SZ  (BT*Hq*Dq)           // 1327104
#define P_OFF  0
#define Q_OFF  (P_OFF + P_SZ)
#define V_OFF  (Q_OFF + QV_SZ)
#define WT_OFF (V_OFF + QV_SZ)      // Wt[128][2048]
#define WT_SZ  (2048*128)
#define FWT_OFF (WT_OFF + WT_SZ)    // fwT[128][128]
#define FWT_SZ  (128*128)

__device__ __forceinline__ void fma4(float4& a, float s, const float4 v) {
    a.x = fmaf(s, v.x, a.x); a.y = fmaf(s, v.y, a.y);
    a.z = fmaf(s, v.z, a.z); a.w = fmaf(s, v.w, a.w);
}
__device__ __forceinline__ float l1_4(const float4 q, const float4 k) {
    return fabsf(q.x - k.x) + fabsf(q.y - k.y) + fabsf(q.z - k.z) + fabsf(q.w - k.w);
}
__device__ __forceinline__ int imin(int a, int b) { return a < b ? a : b; }

// ---------------------------------------------------------------------------
// K0: transpose wqkv_w (2048x128 -> Wt 128x2048) and fanout_w (128x128 -> fwT)
// ---------------------------------------------------------------------------
__global__ __launch_bounds__(256) void k_transpose(
    const float* __restrict__ w, const float* __restrict__ fw,
    float* __restrict__ wt, float* __restrict__ fwt)
{
    __shared__ float tile[32][33];
    const int bx = blockIdx.x, by = blockIdx.y;
    const float* src; float* dst; int N, n0;
    if (bx < 64) { src = w;  dst = wt;  N = 2048; n0 = bx * 32; }
    else         { src = fw; dst = fwt; N = 128;  n0 = (bx - 64) * 32; }
    const int k0 = by * 32;
    const int tx = threadIdx.x & 31, ty = threadIdx.x >> 5;   // 32 x 8
    #pragma unroll
    for (int i = ty; i < 32; i += 8)
        tile[i][tx] = src[(size_t)(n0 + i) * Dq + k0 + tx];
    __syncthreads();
    #pragma unroll
    for (int i = ty; i < 32; i += 8)
        dst[(size_t)(k0 + i) * N + n0 + tx] = tile[tx][i];
}

// ---------------------------------------------------------------------------
// K1: QKV GEMM. grid (54, 8): 24 rows x (head: 128 q + 128 v cols) per block.
// 256 thr = 32 ng x 8 tg (3 rows each). LDS-free; Wt coalesced; x via L1.
// ---------------------------------------------------------------------------
__global__ __launch_bounds__(256) void k_qkv(
    const float* __restrict__ x, const float* __restrict__ Wt,
    const float* __restrict__ bias, const float* __restrict__ he,
    float* __restrict__ Qo, float* __restrict__ Vo)
{
    const int tid = threadIdx.x;
    const int ng = tid & 31, tg = tid >> 5;
    const int row0 = blockIdx.x * 24 + tg * 3;      // 54*24 = 1296 exact
    const int h = blockIdx.y;
    const int nq = h * 256 + ng * 4;                // q col base; v at +128

    float4 acc[3][2];
    const float4 bq = *(const float4*)(bias + nq);
    const float4 bv = *(const float4*)(bias + nq + 128);
    #pragma unroll
    for (int i = 0; i < 3; ++i) { acc[i][0] = bq; acc[i][1] = bv; }

    const float* xb  = x + (size_t)row0 * Dq;
    const float* wt0 = Wt + nq;

    #pragma unroll 2
    for (int k = 0; k < Dq; k += 4) {
        float4 b4[4][2];
        #pragma unroll
        for (int kk = 0; kk < 4; ++kk) {
            b4[kk][0] = *(const float4*)(wt0 + (size_t)(k + kk) * 2048);
            b4[kk][1] = *(const float4*)(wt0 + (size_t)(k + kk) * 2048 + 128);
        }
        #pragma unroll
        for (int i = 0; i < 3; ++i) {
            const float4 a = *(const float4*)(xb + (size_t)i * Dq + k);
            #pragma unroll
            for (int j = 0; j < 2; ++j) {
                fma4(acc[i][j], a.x, b4[0][j]);
                fma4(acc[i][j], a.y, b4[1][j]);
                fma4(acc[i][j], a.z, b4[2][j]);
                fma4(acc[i][j], a.w, b4[3][j]);
            }
        }
    }
    const float hescale = he[h];
    #pragma unroll
    for (int i = 0; i < 3; ++i) {
        const size_t row = row0 + i;
        float* qdst = Qo + (row * Hq + h) * Dq + ng * 4;
        float* vdst = Vo + (row * Hq + h) * Dq + ng * 4;
        *(float4*)qdst = acc[i][0];
        float4 vs;
        vs.x = acc[i][1].x * hescale; vs.y = acc[i][1].y * hescale;
        vs.z = acc[i][1].z * hescale; vs.w = acc[i][1].w * hescale;
        *(float4*)vdst = vs;
    }
}

// ---------------------------------------------------------------------------
// K2: scores + softmax + P + ap.  grid (2, 8, 16) = (t-half, h, b), block 256.
// K = x*wk staged in LDS (stride 132). 231 threads: 11 tg x 21 sg, tile 4t x 4s
// with strided coverage (t = tg+11i, s = sg+21j) for conflict-free LDS reads
// and broadcast Q global reads. Softmax rows in LDS (stride 85, conflict-free),
// cooperative coalesced store of P[b][h][s][t(pad 84)] and ap.
// ---------------------------------------------------------------------------
__global__ __launch_bounds__(256) void k_scores(
    const float* __restrict__ x, const float* __restrict__ Q,
    const float* __restrict__ wk, const float* __restrict__ msk,
    float* __restrict__ P, float* __restrict__ out)
{
    __shared__ float Kl[84 * 132];
    __shared__ float sc[44 * 85];
    __shared__ float rsum[44];
    const int tid = threadIdx.x;
    const int th = blockIdx.x, h = blockIdx.y, b = blockIdx.z;
    const int t0g = th * 41;

    // stage K = x * wk[h]  (81 rows x 128, row stride 132 floats)
    {
        const float* wkb = wk + (size_t)h * Dq;
        for (int idx = tid; idx < Tq * 32; idx += 256) {
            const int r = idx >> 5, c = idx & 31;
            const float4 xv = *(const float4*)(x + (size_t)(b * Tq + r) * Dq + c * 4);
            const float4 wv = *(const float4*)(wkb + c * 4);
            float4 kv;
            kv.x = xv.x * wv.x; kv.y = xv.y * wv.y;
            kv.z = xv.z * wv.z; kv.w = xv.w * wv.w;
            *(float4*)(&Kl[r * 132 + c * 4]) = kv;
        }
    }
    __syncthreads();

    if (tid < 231) {
        const int tg = tid / 21, sg = tid % 21;
        const float* qrow[4];
        #pragma unroll
        for (int i = 0; i < 4; ++i) {
            const int tgl = imin(t0g + tg + 11 * i, Tq - 1);
            qrow[i] = Q + ((size_t)(b * Tq + tgl) * Hq + h) * Dq;
        }
        float4 acc[4];
        #pragma unroll
        for (int i = 0; i < 4; ++i) acc[i] = make_float4(0.f, 0.f, 0.f, 0.f);

        #pragma unroll 4
        for (int k4 = 0; k4 < 32; ++k4) {
            float4 kv[4];
            #pragma unroll
            for (int j = 0; j < 4; ++j)
                kv[j] = *(const float4*)(&Kl[(sg + 21 * j) * 132 + k4 * 4]);
            #pragma unroll
            for (int i = 0; i < 4; ++i) {
                const float4 qv = *(const float4*)(qrow[i] + k4 * 4);
                acc[i].x += l1_4(qv, kv[0]);
                acc[i].y += l1_4(qv, kv[1]);
                acc[i].z += l1_4(qv, kv[2]);
                acc[i].w += l1_4(qv, kv[3]);
            }
        }
        const float ns = -0.08838834764831845f;   // -1/sqrt(128)
        #pragma unroll
        for (int i = 0; i < 4; ++i) {
            const int tl = tg + 11 * i;            // 0..43; rows >= nt unused
            sc[tl * 85 + sg]      = acc[i].x * ns;
            sc[tl * 85 + sg + 21] = acc[i].y * ns;
            sc[tl * 85 + sg + 42] = acc[i].z * ns;
            sc[tl * 85 + sg + 63] = acc[i].w * ns;
        }
    }
    __syncthreads();

    const int nt = th ? 40 : 41;
    if (tid < nt) {
        float* row = sc + tid * 85;
        float m = -1e30f;
        for (int s = 0; s < Tq; ++s) m = fmaxf(m, row[s]);
        float sum = 0.f;
        for (int s = 0; s < Tq; ++s) { const float e = __expf(row[s] - m); row[s] = e; sum += e; }
        rsum[tid] = 1.0f / sum;
    }
    __syncthreads();

    for (int idx = tid; idx < 41 * Tq; idx += 256) {
        const int s = idx / 41, tl = idx - s * 41;
        if (tl < nt) {
            const int tg2 = t0g + tl;
            const float mv = msk[((size_t)h * Tq + tg2) * Tq + s];
            const float pm = sc[tl * 85 + s] * rsum[tl] * mv;
            P[((size_t)(b * Hq + h) * Tq + s) * PT + tg2] = pm;
            if (b == 0) out[BTD + ((size_t)tg2 * Tq + s) * Hq + h] = pm - 1.0f + mv;
        }
    }
}

// ---------------------------------------------------------------------------
// K3: bo einsum + quick-gelu + fanout + residual. grid (21, 16) = (t-chunk4, b),
// block 256 = 4 waves. P tile staged to LDS ([h][s][4t], broadcast b128 reads);
// wave w sums heads {2w,2w+1}; lanes = d/2. LDS reduce -> gelu -> per-wave
// fanout GEMM row -> residual store.
// ---------------------------------------------------------------------------
__global__ __launch_bounds__(256) void k_out(
    const float* __restrict__ x, const float* __restrict__ P,
    const float* __restrict__ V, const float* __restrict__ fwT,
    const float* __restrict__ fb, float* __restrict__ out)
{
    __shared__ float Pl[Hq * Tq * 4];       // [h][s][tt]
    __shared__ float bo_part[4][4][128];
    __shared__ float zs[4][128];
    const int tid = threadIdx.x;
    const int t0 = blockIdx.x * 4, b = blockIdx.y;

    // stage P tile: 8 h x 81 s x 4 t (aligned float4: PT=84, t0 % 4 == 0)
    for (int idx = tid; idx < Hq * Tq; idx += 256) {
        const int hh = idx / Tq, s = idx - hh * Tq;
        ((float4*)Pl)[idx] =
            *(const float4*)(P + ((size_t)(b * Hq + hh) * Tq + s) * PT + t0);
    }
    __syncthreads();

    const int w = tid >> 6, lane = tid & 63;
    {
        const int d0 = lane * 2;
        const int h0 = w * 2, h1 = h0 + 1;
        float2 acc[4];
        #pragma unroll
        for (int i = 0; i < 4; ++i) acc[i] = make_float2(0.f, 0.f);
        const float* v0p = V + ((size_t)(b * Tq) * Hq + h0) * Dq + d0;
        const float* v1p = V + ((size_t)(b * Tq) * Hq + h1) * Dq + d0;
        #pragma unroll 3
        for (int s = 0; s < Tq; ++s) {
            const float2 v0 = *(const float2*)(v0p + (size_t)s * Hq * Dq);
            const float2 v1 = *(const float2*)(v1p + (size_t)s * Hq * Dq);
            const float4 p0 = ((const float4*)Pl)[h0 * Tq + s];
            const float4 p1 = ((const float4*)Pl)[h1 * Tq + s];
            acc[0].x += p0.x * v0.x + p1.x * v1.x;
            acc[0].y += p0.x * v0.y + p1.x * v1.y;
            acc[1].x += p0.y * v0.x + p1.y * v1.x;
            acc[1].y += p0.y * v0.y + p1.y * v1.y;
            acc[2].x += p0.z * v0.x + p1.z * v1.x;
            acc[2].y += p0.z * v0.y + p1.z * v1.y;
            acc[3].x += p0.w * v0.x + p1.w * v1.x;
            acc[3].y += p0.w * v0.y + p1.w * v1.y;
        }
        #pragma unroll
        for (int i = 0; i < 4; ++i) {
            bo_part[w][i][d0]     = acc[i].x;
            bo_part[w][i][d0 + 1] = acc[i].y;
        }
    }
    __syncthreads();

    #pragma unroll
    for (int idx = tid; idx < 512; idx += 256) {
        const int t = idx >> 7, d = idx & 127;
        const float bo = bo_part[0][t][d] + bo_part[1][t][d]
                       + bo_part[2][t][d] + bo_part[3][t][d];
        const float tt = bo + 4.0f;
        const float sg = 1.0f / (1.0f + __expf(-1.702f * tt));
        zs[t][d] = tt * sg - 4.0f;
    }
    __syncthreads();

    {
        const int d0 = lane * 2;
        float2 a2 = make_float2(0.f, 0.f);
        #pragma unroll 8
        for (int k = 0; k < Dq; ++k) {
            const float zk = zs[w][k];
            const float2 wv = *(const float2*)(fwT + (size_t)k * Dq + d0);
            a2.x = fmaf(zk, wv.x, a2.x);
            a2.y = fmaf(zk, wv.y, a2.y);
        }
        const int tg2 = t0 + w;
        if (tg2 < Tq) {
            const float2 xb  = *(const float2*)(x + ((size_t)b * Tq + tg2) * Dq + d0);
            const float2 fb2 = *(const float2*)(fb + d0);
            float2 o;
            o.x = xb.x + a2.x + fb2.x;
            o.y = xb.y + a2.y + fb2.y;
            *(float2*)(out + ((size_t)b * Tq + tg2) * Dq + d0) = o;
        }
    }
}

extern "C" void kernel_launch(void* const* d_in, const int* in_sizes, int n_in,
                              void* d_out, int out_size, void* d_ws, size_t ws_size,
                              hipStream_t stream) {
    const float* x        = (const float*)d_in[0];
    const float* msk      = (const float*)d_in[1];
    const float* wqkv_w   = (const float*)d_in[2];
    const float* wqkv_b   = (const float*)d_in[3];
    const float* wk_w     = (const float*)d_in[4];
    const float* fanout_w = (const float*)d_in[5];
    const float* fanout_b = (const float*)d_in[6];
    const float* he       = (const float*)d_in[7];
    float* out = (float*)d_out;
    float* ws  = (float*)d_ws;

    float* P   = ws + P_OFF;
    float* Q   = ws + Q_OFF;
    float* V   = ws + V_OFF;
    float* Wt  = ws + WT_OFF;
    float* fwT = ws + FWT_OFF;

    k_transpose<<<dim3(68, 4), 256, 0, stream>>>(wqkv_w, fanout_w, Wt, fwT);
    k_qkv<<<dim3(54, 8), 256, 0, stream>>>(x, Wt, wqkv_b, he, Q, V);
    k_scores<<<dim3(2, 8, 16), 256, 0, stream>>>(x, Q, wk_w, msk, P, out);
    k_out<<<dim3(21, 16), 256, 0, stream>>>(x, P, V, fwT, fanout_b, out);
}

// Round 3
// 152.393 us; speedup vs baseline: 1.1854x; 1.1808x over previous
//
#include <hip/hip_runtime.h>
#include <math.h>

#define Bq 16
#define Tq 81
#define Dq 128
#define Hq 8
#define BT (Bq*Tq)          // 1296
#define BTD (Bq*Tq*Dq)      // 165888 (out region 0)
#define PT 84               // padded t-stride of P (16B-aligned float4 rows)
// ws layout (floats)
#define P_SZ   (Bq*Hq*Tq*PT)        // 870912
#define QV_SZ  (BT*Hq*Dq)           // 1327104
#define P_OFF  0
#define Q_OFF  (P_OFF + P_SZ)
#define V_OFF  (Q_OFF + QV_SZ)
#define WT_OFF (V_OFF + QV_SZ)      // Wt[128][2048]
#define WT_SZ  (2048*128)

__device__ __forceinline__ void fma4(float4& a, float s, const float4 v) {
    a.x = fmaf(s, v.x, a.x); a.y = fmaf(s, v.y, a.y);
    a.z = fmaf(s, v.z, a.z); a.w = fmaf(s, v.w, a.w);
}
__device__ __forceinline__ float l1_4(const float4 q, const float4 k) {
    return fabsf(q.x - k.x) + fabsf(q.y - k.y) + fabsf(q.z - k.z) + fabsf(q.w - k.w);
}
__device__ __forceinline__ int imin(int a, int b) { return a < b ? a : b; }

// ---------------------------------------------------------------------------
// K0: transpose wqkv_w (2048x128 -> Wt 128x2048). grid (64,4) block 256.
// ---------------------------------------------------------------------------
__global__ __launch_bounds__(256) void k_transpose(
    const float* __restrict__ w, float* __restrict__ wt)
{
    __shared__ float tile[32][33];
    const int n0 = blockIdx.x * 32, k0 = blockIdx.y * 32;
    const int tx = threadIdx.x & 31, ty = threadIdx.x >> 5;   // 32 x 8
    #pragma unroll
    for (int i = ty; i < 32; i += 8)
        tile[i][tx] = w[(size_t)(n0 + i) * Dq + k0 + tx];
    __syncthreads();
    #pragma unroll
    for (int i = ty; i < 32; i += 8)
        wt[(size_t)(k0 + i) * 2048 + n0 + tx] = tile[tx][i];
}

// ---------------------------------------------------------------------------
// K1: QKV GEMM. grid (81, 16): 16 rows x 128 cols per block. Col-tile by maps
// to head h=by>>1, (by&1 ? V : Q). x tile staged in LDS; thread tile 2r x 4c
// (acc 8 VGPRs — no spill). 1296 blocks -> ~5 waves/SIMD.
// ---------------------------------------------------------------------------
__global__ __launch_bounds__(256) void k_qkv(
    const float* __restrict__ x, const float* __restrict__ Wt,
    const float* __restrict__ bias, const float* __restrict__ he,
    float* __restrict__ Qo, float* __restrict__ Vo)
{
    __shared__ float xs[16][128];
    const int tid = threadIdx.x;
    const int cg = tid & 31, rg = tid >> 5;
    const int r0 = blockIdx.x * 16;               // 81*16 = 1296 exact
    const int n0 = blockIdx.y * 128;              // global col base
    const int h  = blockIdx.y >> 1;
    const int isV = blockIdx.y & 1;

    // stage x tile (16 x 128)
    #pragma unroll
    for (int idx = tid; idx < 16 * 32; idx += 256) {
        const int r = idx >> 5, c = idx & 31;
        ((float4*)xs)[idx] = *(const float4*)(x + (size_t)(r0 + r) * Dq + c * 4);
    }
    __syncthreads();

    float4 acc[2];
    acc[0] = acc[1] = *(const float4*)(bias + n0 + cg * 4);

    const float* wt0 = Wt + n0 + cg * 4;
    #pragma unroll 2
    for (int k = 0; k < Dq; k += 4) {
        float4 w4[4];
        #pragma unroll
        for (int kk = 0; kk < 4; ++kk)
            w4[kk] = *(const float4*)(wt0 + (size_t)(k + kk) * 2048);
        #pragma unroll
        for (int i = 0; i < 2; ++i) {
            const float4 a = *(const float4*)(&xs[rg * 2 + i][k]);
            fma4(acc[i], a.x, w4[0]);
            fma4(acc[i], a.y, w4[1]);
            fma4(acc[i], a.z, w4[2]);
            fma4(acc[i], a.w, w4[3]);
        }
    }

    const float hescale = isV ? he[h] : 1.0f;
    float* dst = (isV ? Vo : Qo);
    #pragma unroll
    for (int i = 0; i < 2; ++i) {
        const size_t row = r0 + rg * 2 + i;
        float4 o;
        o.x = acc[i].x * hescale; o.y = acc[i].y * hescale;
        o.z = acc[i].z * hescale; o.w = acc[i].w * hescale;
        *(float4*)(dst + (row * Hq + h) * Dq + cg * 4) = o;
    }
}

// ---------------------------------------------------------------------------
// K2: scores + softmax + P + ap.  grid (2, 8, 16) = (t-half, h, b), block 512.
// K = x*wk staged in LDS. 441 threads: 21 tg (2t) x 21 sg (4s strided).
// Wave-parallel softmax (8 waves, shfl reductions). Coalesced P store.
// ---------------------------------------------------------------------------
__global__ __launch_bounds__(512) void k_scores(
    const float* __restrict__ x, const float* __restrict__ Q,
    const float* __restrict__ wk, const float* __restrict__ msk,
    float* __restrict__ P, float* __restrict__ out)
{
    __shared__ float Kl[84 * 132];
    __shared__ float sc[44 * 85];
    __shared__ float rsum[44];
    const int tid = threadIdx.x;
    const int th = blockIdx.x, h = blockIdx.y, b = blockIdx.z;
    const int t0g = th * 41;
    const int nt = th ? 40 : 41;

    // stage K = x * wk[h]  (81 rows x 128, row stride 132 floats)
    {
        const float* wkb = wk + (size_t)h * Dq;
        for (int idx = tid; idx < Tq * 32; idx += 512) {
            const int r = idx >> 5, c = idx & 31;
            const float4 xv = *(const float4*)(x + (size_t)(b * Tq + r) * Dq + c * 4);
            const float4 wv = *(const float4*)(wkb + c * 4);
            float4 kv;
            kv.x = xv.x * wv.x; kv.y = xv.y * wv.y;
            kv.z = xv.z * wv.z; kv.w = xv.w * wv.w;
            *(float4*)(&Kl[r * 132 + c * 4]) = kv;
        }
    }
    __syncthreads();

    if (tid < 441) {
        const int tg = tid / 21, sg = tid % 21;
        const int tl0 = tg * 2;
        const float* qrow[2];
        #pragma unroll
        for (int i = 0; i < 2; ++i) {
            const int t = imin(t0g + tl0 + i, Tq - 1);
            qrow[i] = Q + ((size_t)(b * Tq + t) * Hq + h) * Dq;
        }
        float4 acc[2];
        acc[0] = acc[1] = make_float4(0.f, 0.f, 0.f, 0.f);

        #pragma unroll 4
        for (int k4 = 0; k4 < 32; ++k4) {
            float4 kv[4];
            #pragma unroll
            for (int j = 0; j < 4; ++j)
                kv[j] = *(const float4*)(&Kl[(sg + 21 * j) * 132 + k4 * 4]);
            #pragma unroll
            for (int i = 0; i < 2; ++i) {
                const float4 qv = *(const float4*)(qrow[i] + k4 * 4);
                acc[i].x += l1_4(qv, kv[0]);
                acc[i].y += l1_4(qv, kv[1]);
                acc[i].z += l1_4(qv, kv[2]);
                acc[i].w += l1_4(qv, kv[3]);
            }
        }
        const float ns = -0.08838834764831845f;   // -1/sqrt(128)
        #pragma unroll
        for (int i = 0; i < 2; ++i) {
            const int tl = tl0 + i;               // 0..41 (<44)
            sc[tl * 85 + sg]      = acc[i].x * ns;
            sc[tl * 85 + sg + 21] = acc[i].y * ns;
            sc[tl * 85 + sg + 42] = acc[i].z * ns;
            sc[tl * 85 + sg + 63] = acc[i].w * ns;
        }
    }
    __syncthreads();

    // wave-parallel softmax: wave w handles rows w, w+8, ...
    {
        const int w = tid >> 6, lane = tid & 63;
        for (int r = w; r < nt; r += 8) {
            float* row = sc + r * 85;
            const bool hi = (lane + 64) < Tq;
            const float v0 = row[lane];
            const float v1 = hi ? row[lane + 64] : -1e30f;
            float m = fmaxf(v0, v1);
            #pragma unroll
            for (int off = 32; off > 0; off >>= 1)
                m = fmaxf(m, __shfl_xor(m, off));
            const float e0 = __expf(v0 - m);
            const float e1 = hi ? __expf(v1 - m) : 0.f;
            float s = e0 + e1;
            #pragma unroll
            for (int off = 32; off > 0; off >>= 1)
                s += __shfl_xor(s, off);
            row[lane] = e0;
            if (hi) row[lane + 64] = e1;
            if (lane == 0) rsum[r] = 1.0f / s;
        }
    }
    __syncthreads();

    for (int idx = tid; idx < 41 * Tq; idx += 512) {
        const int s = idx / 41, tl = idx - s * 41;
        if (tl < nt) {
            const int tg2 = t0g + tl;
            const float mv = msk[((size_t)h * Tq + tg2) * Tq + s];
            const float pm = sc[tl * 85 + s] * rsum[tl] * mv;
            P[((size_t)(b * Hq + h) * Tq + s) * PT + tg2] = pm;
            if (b == 0) out[BTD + ((size_t)tg2 * Tq + s) * Hq + h] = pm - 1.0f + mv;
        }
    }
}

// ---------------------------------------------------------------------------
// K3: bo einsum + quick-gelu + fanout + residual. grid (41, 16) = (t-chunk2, b),
// block 256 = 4 waves (~10 waves/CU). Wave w sums heads {2w,2w+1}; lanes = d/2.
// LDS reduce -> gelu -> fanout via untransposed fw rows (contiguous dot).
// ---------------------------------------------------------------------------
__global__ __launch_bounds__(256) void k_out(
    const float* __restrict__ x, const float* __restrict__ P,
    const float* __restrict__ V, const float* __restrict__ fw,
    const float* __restrict__ fb, float* __restrict__ out)
{
    __shared__ float Pl[Hq][Tq][2];
    __shared__ float bo_part[4][2][128];
    __shared__ float zs[2][128];
    const int tid = threadIdx.x;
    const int t0 = blockIdx.x * 2, b = blockIdx.y;

    // stage P tile: 8 h x 81 s x 2 t (float2; PT=84, t0 even -> aligned)
    for (int idx = tid; idx < Hq * Tq; idx += 256) {
        const int hh = idx / Tq, s = idx - hh * Tq;
        *(float2*)(&Pl[hh][s][0]) =
            *(const float2*)(P + ((size_t)(b * Hq + hh) * Tq + s) * PT + t0);
    }
    __syncthreads();

    const int w = tid >> 6, lane = tid & 63;
    {
        const int d0 = lane * 2;
        const int h0 = w * 2, h1 = h0 + 1;
        float2 acc[2];
        acc[0] = acc[1] = make_float2(0.f, 0.f);
        const float* v0p = V + ((size_t)(b * Tq) * Hq + h0) * Dq + d0;
        const float* v1p = V + ((size_t)(b * Tq) * Hq + h1) * Dq + d0;
        #pragma unroll 3
        for (int s = 0; s < Tq; ++s) {
            const float2 v0 = *(const float2*)(v0p + (size_t)s * Hq * Dq);
            const float2 v1 = *(const float2*)(v1p + (size_t)s * Hq * Dq);
            const float2 p0 = *(const float2*)(&Pl[h0][s][0]);
            const float2 p1 = *(const float2*)(&Pl[h1][s][0]);
            acc[0].x += p0.x * v0.x + p1.x * v1.x;
            acc[0].y += p0.x * v0.y + p1.x * v1.y;
            acc[1].x += p0.y * v0.x + p1.y * v1.x;
            acc[1].y += p0.y * v0.y + p1.y * v1.y;
        }
        #pragma unroll
        for (int i = 0; i < 2; ++i) {
            bo_part[w][i][d0]     = acc[i].x;
            bo_part[w][i][d0 + 1] = acc[i].y;
        }
    }
    __syncthreads();

    {   // gelu: one (t,d) per thread
        const int t = tid >> 7, d = tid & 127;
        const float bo = bo_part[0][t][d] + bo_part[1][t][d]
                       + bo_part[2][t][d] + bo_part[3][t][d];
        const float tt = bo + 4.0f;
        const float sg = 1.0f / (1.0f + __expf(-1.702f * tt));
        zs[t][d] = tt * sg - 4.0f;
    }
    __syncthreads();

    {   // fanout: one output (t, n) per thread; fw row n is contiguous
        const int t = tid >> 7, n = tid & 127;
        const float* fwr = fw + (size_t)n * Dq;
        float a = 0.f;
        #pragma unroll 8
        for (int k4 = 0; k4 < 32; ++k4) {
            const float4 z4 = *(const float4*)(&zs[t][k4 * 4]);
            const float4 w4 = *(const float4*)(fwr + k4 * 4);
            a += z4.x * w4.x + z4.y * w4.y + z4.z * w4.z + z4.w * w4.w;
        }
        const int tg2 = t0 + t;
        if (tg2 < Tq) {
            const size_t o = ((size_t)b * Tq + tg2) * Dq + n;
            out[o] = x[o] + a + fb[n];
        }
    }
}

extern "C" void kernel_launch(void* const* d_in, const int* in_sizes, int n_in,
                              void* d_out, int out_size, void* d_ws, size_t ws_size,
                              hipStream_t stream) {
    const float* x        = (const float*)d_in[0];
    const float* msk      = (const float*)d_in[1];
    const float* wqkv_w   = (const float*)d_in[2];
    const float* wqkv_b   = (const float*)d_in[3];
    const float* wk_w     = (const float*)d_in[4];
    const float* fanout_w = (const float*)d_in[5];
    const float* fanout_b = (const float*)d_in[6];
    const float* he       = (const float*)d_in[7];
    float* out = (float*)d_out;
    float* ws  = (float*)d_ws;

    float* P   = ws + P_OFF;
    float* Q   = ws + Q_OFF;
    float* V   = ws + V_OFF;
    float* Wt  = ws + WT_OFF;

    k_transpose<<<dim3(64, 4), 256, 0, stream>>>(wqkv_w, Wt);
    k_qkv<<<dim3(81, 16), 256, 0, stream>>>(x, Wt, wqkv_b, he, Q, V);
    k_scores<<<dim3(2, 8, 16), 512, 0, stream>>>(x, Q, wk_w, msk, P, out);
    k_out<<<dim3(41, 16), 256, 0, stream>>>(x, P, V, fanout_w, fanout_b, out);
}

// Round 4
// 150.404 us; speedup vs baseline: 1.2011x; 1.0132x over previous
//
#include <hip/hip_runtime.h>
#include <math.h>

#define Bq 16
#define Tq 81
#define Dq 128
#define Hq 8
#define BT (Bq*Tq)          // 1296
#define BTD (Bq*Tq*Dq)      // 165888 (out region 0)
#define PS 84               // padded s-stride of P
// P layout: [b][t][h][s(pad 84)]
#define P_SZ   (Bq*Tq*Hq*PS)        // 870912
#define QV_SZ  (BT*Hq*Dq)           // 1327104
#define P_OFF  0
#define Q_OFF  (P_OFF + P_SZ)
#define V_OFF  (Q_OFF + QV_SZ)
#define WT_OFF (V_OFF + QV_SZ)      // Wt[128][2048]
#define WT_SZ  (2048*128)

__device__ __forceinline__ void fma4(float4& a, float s, const float4 v) {
    a.x = fmaf(s, v.x, a.x); a.y = fmaf(s, v.y, a.y);
    a.z = fmaf(s, v.z, a.z); a.w = fmaf(s, v.w, a.w);
}
__device__ __forceinline__ float l1_4(const float4 q, const float4 k) {
    return fabsf(q.x - k.x) + fabsf(q.y - k.y) + fabsf(q.z - k.z) + fabsf(q.w - k.w);
}
__device__ __forceinline__ int imin(int a, int b) { return a < b ? a : b; }

// ---------------------------------------------------------------------------
// K0: transpose wqkv_w (2048x128 -> Wt 128x2048). grid (64,4) block 256.
// ---------------------------------------------------------------------------
__global__ __launch_bounds__(256) void k_transpose(
    const float* __restrict__ w, float* __restrict__ wt)
{
    __shared__ float tile[32][33];
    const int n0 = blockIdx.x * 32, k0 = blockIdx.y * 32;
    const int tx = threadIdx.x & 31, ty = threadIdx.x >> 5;   // 32 x 8
    #pragma unroll
    for (int i = ty; i < 32; i += 8)
        tile[i][tx] = w[(size_t)(n0 + i) * Dq + k0 + tx];
    __syncthreads();
    #pragma unroll
    for (int i = ty; i < 32; i += 8)
        wt[(size_t)(k0 + i) * 2048 + n0 + tx] = tile[tx][i];
}

// ---------------------------------------------------------------------------
// K1: QKV GEMM. grid (81, 16): 16 rows x 128 cols per block. Col-tile by maps
// to head h=by>>1, (by&1 ? V : Q). x tile staged in LDS; thread tile 2r x 4c.
// ---------------------------------------------------------------------------
__global__ __launch_bounds__(256) void k_qkv(
    const float* __restrict__ x, const float* __restrict__ Wt,
    const float* __restrict__ bias, const float* __restrict__ he,
    float* __restrict__ Qo, float* __restrict__ Vo)
{
    __shared__ float xs[16][128];
    const int tid = threadIdx.x;
    const int cg = tid & 31, rg = tid >> 5;
    const int r0 = blockIdx.x * 16;               // 81*16 = 1296 exact
    const int n0 = blockIdx.y * 128;              // global col base
    const int h  = blockIdx.y >> 1;
    const int isV = blockIdx.y & 1;

    #pragma unroll
    for (int idx = tid; idx < 16 * 32; idx += 256) {
        const int r = idx >> 5, c = idx & 31;
        ((float4*)xs)[idx] = *(const float4*)(x + (size_t)(r0 + r) * Dq + c * 4);
    }
    __syncthreads();

    float4 acc[2];
    acc[0] = acc[1] = *(const float4*)(bias + n0 + cg * 4);

    const float* wt0 = Wt + n0 + cg * 4;
    #pragma unroll 2
    for (int k = 0; k < Dq; k += 4) {
        float4 w4[4];
        #pragma unroll
        for (int kk = 0; kk < 4; ++kk)
            w4[kk] = *(const float4*)(wt0 + (size_t)(k + kk) * 2048);
        #pragma unroll
        for (int i = 0; i < 2; ++i) {
            const float4 a = *(const float4*)(&xs[rg * 2 + i][k]);
            fma4(acc[i], a.x, w4[0]);
            fma4(acc[i], a.y, w4[1]);
            fma4(acc[i], a.z, w4[2]);
            fma4(acc[i], a.w, w4[3]);
        }
    }

    const float hescale = isV ? he[h] : 1.0f;
    float* dst = (isV ? Vo : Qo);
    #pragma unroll
    for (int i = 0; i < 2; ++i) {
        const size_t row = r0 + rg * 2 + i;
        float4 o;
        o.x = acc[i].x * hescale; o.y = acc[i].y * hescale;
        o.z = acc[i].z * hescale; o.w = acc[i].w * hescale;
        *(float4*)(dst + (row * Hq + h) * Dq + cg * 4) = o;
    }
}

// ---------------------------------------------------------------------------
// K2: scores + softmax + P. grid (4, 8, 16) = (t-quarter, h, b), block 256.
// K = x*wk staged in LDS (81 x 132). 252 threads: 21 tg (1t) x 12 sg (7s
// strided by 12). Wave-parallel softmax. P store [b][t][h][s] coalesced.
// ---------------------------------------------------------------------------
__global__ __launch_bounds__(256) void k_scores(
    const float* __restrict__ x, const float* __restrict__ Q,
    const float* __restrict__ wk, const float* __restrict__ msk,
    float* __restrict__ P)
{
    __shared__ float Kl[81 * 132];
    __shared__ float sc[21 * 85];
    __shared__ float rsum[24];
    const int tid = threadIdx.x;
    const int tq = blockIdx.x, h = blockIdx.y, b = blockIdx.z;
    const int t0g = tq * 21;
    const int nt = (tq == 3) ? 18 : 21;

    // stage K = x * wk[h]  (81 rows x 128, row stride 132 floats)
    {
        const float* wkb = wk + (size_t)h * Dq;
        for (int idx = tid; idx < Tq * 32; idx += 256) {
            const int r = idx >> 5, c = idx & 31;
            const float4 xv = *(const float4*)(x + (size_t)(b * Tq + r) * Dq + c * 4);
            const float4 wv = *(const float4*)(wkb + c * 4);
            float4 kv;
            kv.x = xv.x * wv.x; kv.y = xv.y * wv.y;
            kv.z = xv.z * wv.z; kv.w = xv.w * wv.w;
            *(float4*)(&Kl[r * 132 + c * 4]) = kv;
        }
    }
    __syncthreads();

    if (tid < 252) {
        const int tg = tid / 12, sg = tid % 12;
        const int t = imin(t0g + tg, Tq - 1);
        const float* qrow = Q + ((size_t)(b * Tq + t) * Hq + h) * Dq;

        int sidx[7];
        #pragma unroll
        for (int j = 0; j < 7; ++j) sidx[j] = imin(sg + 12 * j, Tq - 1);

        float acc[7];
        #pragma unroll
        for (int j = 0; j < 7; ++j) acc[j] = 0.f;

        #pragma unroll 4
        for (int k4 = 0; k4 < 32; ++k4) {
            const float4 qv = *(const float4*)(qrow + k4 * 4);
            #pragma unroll
            for (int j = 0; j < 7; ++j) {
                const float4 kv = *(const float4*)(&Kl[sidx[j] * 132 + k4 * 4]);
                acc[j] += l1_4(qv, kv);
            }
        }
        const float ns = -0.08838834764831845f;   // -1/sqrt(128)
        #pragma unroll
        for (int j = 0; j < 7; ++j) {
            const int s = sg + 12 * j;            // < 84; slots 81..83 unused
            sc[tg * 85 + s] = acc[j] * ns;
        }
    }
    __syncthreads();

    // wave-parallel softmax: wave w handles rows w, w+4, ...
    {
        const int w = tid >> 6, lane = tid & 63;
        for (int r = w; r < nt; r += 4) {
            float* row = sc + r * 85;
            const bool hi = (lane + 64) < Tq;
            const float v0 = row[lane];
            const float v1 = hi ? row[lane + 64] : -1e30f;
            float m = fmaxf(v0, v1);
            #pragma unroll
            for (int off = 32; off > 0; off >>= 1)
                m = fmaxf(m, __shfl_xor(m, off));
            const float e0 = __expf(v0 - m);
            const float e1 = hi ? __expf(v1 - m) : 0.f;
            float s = e0 + e1;
            #pragma unroll
            for (int off = 32; off > 0; off >>= 1)
                s += __shfl_xor(s, off);
            row[lane] = e0;
            if (hi) row[lane + 64] = e1;
            if (lane == 0) rsum[r] = 1.0f / s;
        }
    }
    __syncthreads();

    // store P[b][t][h][s]: consecutive tid -> consecutive s (coalesced)
    for (int idx = tid; idx < nt * Tq; idx += 256) {
        const int tl = idx / Tq, s = idx - tl * Tq;
        const int tg2 = t0g + tl;
        const float mv = msk[((size_t)h * Tq + tg2) * Tq + s];
        const float pm = sc[tl * 85 + s] * rsum[tl] * mv;
        P[(((size_t)b * Tq + tg2) * Hq + h) * PS + s] = pm;
    }
}

// ---------------------------------------------------------------------------
// K2b: ap output. grid (81) = t, block 256. ap[t][s][h] = P[0][t][h][s]-1+msk.
// Writes coalesced (h fastest); reads hit a 2.7 KB L1-resident P slab.
// ---------------------------------------------------------------------------
__global__ __launch_bounds__(256) void k_ap(
    const float* __restrict__ P, const float* __restrict__ msk,
    float* __restrict__ out)
{
    const int t = blockIdx.x;
    const float* Pt = P + ((size_t)t * Hq) * PS;
    float* apb = out + BTD + (size_t)t * Tq * Hq;
    for (int idx = threadIdx.x; idx < Tq * Hq; idx += 256) {
        const int h = idx & 7, s = idx >> 3;
        const float mv = msk[((size_t)h * Tq + t) * Tq + s];
        apb[(size_t)s * Hq + h] = Pt[(size_t)h * PS + s] - 1.0f + mv;
    }
}

// ---------------------------------------------------------------------------
// K3: bo einsum + quick-gelu + fanout + residual. grid (41, 16) = (t-chunk2, b),
// block 256 = 4 waves. P tile [2t][8h][84s] staged contiguously (coalesced).
// Wave w sums heads {2w,2w+1} for both t; lanes = d/2. LDS reduce -> gelu ->
// fanout via untransposed fw rows.
// ---------------------------------------------------------------------------
__global__ __launch_bounds__(256) void k_out(
    const float* __restrict__ x, const float* __restrict__ P,
    const float* __restrict__ V, const float* __restrict__ fw,
    const float* __restrict__ fb, float* __restrict__ out)
{
    __shared__ float Pl[2][Hq][PS];
    __shared__ float bo_part[4][2][128];
    __shared__ float zs[2][128];
    const int tid = threadIdx.x;
    const int t0 = blockIdx.x * 2, b = blockIdx.y;

    // stage P tile: 1344 contiguous floats (t0=80: 2nd half is garbage, unused)
    {
        const float4* src = (const float4*)(P + ((size_t)b * Tq + t0) * Hq * PS);
        #pragma unroll
        for (int idx = tid; idx < 2 * Hq * PS / 4; idx += 256)
            ((float4*)Pl)[idx] = src[idx];
    }
    __syncthreads();

    const int w = tid >> 6, lane = tid & 63;
    {
        const int d0 = lane * 2;
        const int h0 = w * 2, h1 = h0 + 1;
        float2 acc[2];
        acc[0] = acc[1] = make_float2(0.f, 0.f);
        const float* v0p = V + ((size_t)(b * Tq) * Hq + h0) * Dq + d0;
        const float* v1p = V + ((size_t)(b * Tq) * Hq + h1) * Dq + d0;
        #pragma unroll 3
        for (int s = 0; s < Tq; ++s) {
            const float2 v0 = *(const float2*)(v0p + (size_t)s * Hq * Dq);
            const float2 v1 = *(const float2*)(v1p + (size_t)s * Hq * Dq);
            const float p00 = Pl[0][h0][s], p01 = Pl[1][h0][s];
            const float p10 = Pl[0][h1][s], p11 = Pl[1][h1][s];
            acc[0].x += p00 * v0.x + p10 * v1.x;
            acc[0].y += p00 * v0.y + p10 * v1.y;
            acc[1].x += p01 * v0.x + p11 * v1.x;
            acc[1].y += p01 * v0.y + p11 * v1.y;
        }
        #pragma unroll
        for (int i = 0; i < 2; ++i) {
            bo_part[w][i][d0]     = acc[i].x;
            bo_part[w][i][d0 + 1] = acc[i].y;
        }
    }
    __syncthreads();

    {   // gelu: one (t,d) per thread
        const int t = tid >> 7, d = tid & 127;
        const float bo = bo_part[0][t][d] + bo_part[1][t][d]
                       + bo_part[2][t][d] + bo_part[3][t][d];
        const float tt = bo + 4.0f;
        const float sg = 1.0f / (1.0f + __expf(-1.702f * tt));
        zs[t][d] = tt * sg - 4.0f;
    }
    __syncthreads();

    {   // fanout: one output (t, n) per thread; fw row n is contiguous
        const int t = tid >> 7, n = tid & 127;
        const float* fwr = fw + (size_t)n * Dq;
        float a = 0.f;
        #pragma unroll 8
        for (int k4 = 0; k4 < 32; ++k4) {
            const float4 z4 = *(const float4*)(&zs[t][k4 * 4]);
            const float4 w4 = *(const float4*)(fwr + k4 * 4);
            a += z4.x * w4.x + z4.y * w4.y + z4.z * w4.z + z4.w * w4.w;
        }
        const int tg2 = t0 + t;
        if (tg2 < Tq) {
            const size_t o = ((size_t)b * Tq + tg2) * Dq + n;
            out[o] = x[o] + a + fb[n];
        }
    }
}

extern "C" void kernel_launch(void* const* d_in, const int* in_sizes, int n_in,
                              void* d_out, int out_size, void* d_ws, size_t ws_size,
                              hipStream_t stream) {
    const float* x        = (const float*)d_in[0];
    const float* msk      = (const float*)d_in[1];
    const float* wqkv_w   = (const float*)d_in[2];
    const float* wqkv_b   = (const float*)d_in[3];
    const float* wk_w     = (const float*)d_in[4];
    const float* fanout_w = (const float*)d_in[5];
    const float* fanout_b = (const float*)d_in[6];
    const float* he       = (const float*)d_in[7];
    float* out = (float*)d_out;
    float* ws  = (float*)d_ws;

    float* P   = ws + P_OFF;
    float* Q   = ws + Q_OFF;
    float* V   = ws + V_OFF;
    float* Wt  = ws + WT_OFF;

    k_transpose<<<dim3(64, 4), 256, 0, stream>>>(wqkv_w, Wt);
    k_qkv<<<dim3(81, 16), 256, 0, stream>>>(x, Wt, wqkv_b, he, Q, V);
    k_scores<<<dim3(4, 8, 16), 256, 0, stream>>>(x, Q, wk_w, msk, P);
    k_ap<<<dim3(81), 256, 0, stream>>>(P, msk, out);
    k_out<<<dim3(41, 16), 256, 0, stream>>>(x, P, V, fanout_w, fanout_b, out);
}

// Round 5
// 138.455 us; speedup vs baseline: 1.3048x; 1.0863x over previous
//
#include <hip/hip_runtime.h>
#include <math.h>

#define Bq 16
#define Tq 81
#define Dq 128
#define Hq 8
#define BT (Bq*Tq)          // 1296
#define BTD (Bq*Tq*Dq)      // 165888 (out region 0)
#define PS 84               // padded s-stride of P
// ws layout (floats). P: [b][t][h][s(pad 84)]
#define P_SZ   (Bq*Tq*Hq*PS)        // 870912
#define QV_SZ  (BT*Hq*Dq)           // 1327104
#define P_OFF  0
#define Q_OFF  (P_OFF + P_SZ)
#define V_OFF  (Q_OFF + QV_SZ)
#define XB_OFF (V_OFF + QV_SZ)      // xb: 1296x128 bf16 (ushort) = 82944 floats
#define XB_FSZ (BTD/2)
#define WB_OFF (XB_OFF + XB_FSZ)    // Wb: 2048x128 bf16 = 131072 floats

typedef __attribute__((ext_vector_type(8))) short short8;
typedef __attribute__((ext_vector_type(4))) float f32x4;

__device__ __forceinline__ float l1_4(const float4 q, const float4 k) {
    return fabsf(q.x - k.x) + fabsf(q.y - k.y) + fabsf(q.z - k.z) + fabsf(q.w - k.w);
}
__device__ __forceinline__ int imin(int a, int b) { return a < b ? a : b; }
__device__ __forceinline__ unsigned short f2bf(float f) {   // RNE f32 -> bf16
    unsigned u = __float_as_uint(f);
    u += 0x7fffu + ((u >> 16) & 1u);
    return (unsigned short)(u >> 16);
}

// ---------------------------------------------------------------------------
// K0: convert wqkv_w and x to bf16 (row-major, no transpose — MFMA B-operand
// reads W[n][k] along k contiguously). grid 418 x 256.
// ---------------------------------------------------------------------------
__global__ __launch_bounds__(256) void k_prep(
    const float* __restrict__ w, const float* __restrict__ x,
    unsigned short* __restrict__ Wb, unsigned short* __restrict__ xb)
{
    const int NW4 = (Hq * 2 * Dq * Dq) / 4;   // 65536
    const int NX4 = BTD / 4;                  // 41472
    const int idx = blockIdx.x * 256 + threadIdx.x;
    if (idx < NW4) {
        const float4 v = ((const float4*)w)[idx];
        ushort4 o;
        o.x = f2bf(v.x); o.y = f2bf(v.y); o.z = f2bf(v.z); o.w = f2bf(v.w);
        ((ushort4*)Wb)[idx] = o;
    } else if (idx < NW4 + NX4) {
        const int j = idx - NW4;
        const float4 v = ((const float4*)x)[j];
        ushort4 o;
        o.x = f2bf(v.x); o.y = f2bf(v.y); o.z = f2bf(v.z); o.w = f2bf(v.w);
        ((ushort4*)xb)[j] = o;
    }
}

// ---------------------------------------------------------------------------
// K1: QKV GEMM via bf16 MFMA 16x16x32. grid (21, 32), 256 thr = 4 waves.
// Wave w: m-tile mt = bx*4+w (16 rows), n-range n0 = by*64 (4 n-tiles).
// A frag: xb[row=mt*16+(lane&15)][kb + quad*8 ..+7]; B frag: Wb[n0+(lane&15)+
// nt*16][kb + quad*8 ..+7]. C/D: col=lane&15, row=quad*4+reg (m89-verified).
// Epilogue: +bias, *head_enabled for V half, scatter-store f32 to Qo/Vo.
// ---------------------------------------------------------------------------
__global__ __launch_bounds__(256) void k_qkv_mfma(
    const unsigned short* __restrict__ xb, const unsigned short* __restrict__ Wb,
    const float* __restrict__ bias, const float* __restrict__ he,
    float* __restrict__ Qo, float* __restrict__ Vo)
{
    const int tid = threadIdx.x;
    const int w = tid >> 6, lane = tid & 63;
    const int ln = lane & 15, quad = lane >> 4;
    const int mt = blockIdx.x * 4 + w;            // 0..83; 81..83 are tail pads
    const int n0 = blockIdx.y * 64;
    const int h  = blockIdx.y >> 2;
    const int isV = (blockIdx.y >> 1) & 1;
    const int c0 = (blockIdx.y & 1) * 64;

    const int row = mt * 16 + ln;
    const int arow = row < BT ? row : BT - 1;     // clamp tail-tile loads
    const unsigned short* xa  = xb + (size_t)arow * Dq + quad * 8;
    const unsigned short* wb0 = Wb + (size_t)(n0 + ln) * Dq + quad * 8;

    f32x4 acc[4];
    #pragma unroll
    for (int i = 0; i < 4; ++i) acc[i] = (f32x4){0.f, 0.f, 0.f, 0.f};

    #pragma unroll
    for (int kb = 0; kb < Dq; kb += 32) {
        const short8 af = *(const short8*)(xa + kb);
        #pragma unroll
        for (int nt = 0; nt < 4; ++nt) {
            const short8 bf = *(const short8*)(wb0 + (size_t)(nt * 16) * Dq + kb);
            acc[nt] = __builtin_amdgcn_mfma_f32_16x16x32_bf16(af, bf, acc[nt], 0, 0, 0);
        }
    }

    if (mt >= 81) return;
    const float scale = isV ? he[h] : 1.0f;
    float* dst = isV ? Vo : Qo;
    const int gm0 = mt * 16 + quad * 4;           // <= 1292, always in range
    #pragma unroll
    for (int nt = 0; nt < 4; ++nt) {
        const float bn = bias[n0 + nt * 16 + ln];
        #pragma unroll
        for (int r = 0; r < 4; ++r) {
            const int gm = gm0 + r;
            dst[((size_t)gm * Hq + h) * Dq + c0 + nt * 16 + ln] =
                (acc[nt][r] + bn) * scale;
        }
    }
}

// ---------------------------------------------------------------------------
// K2: scores + softmax + P. grid (4, 8, 16) = (t-quarter, h, b), block 256.
// K = x*wk staged in LDS (81 x 132). 252 threads: 21 tg (1t) x 12 sg (7s
// strided by 12). Wave-parallel softmax. P store [b][t][h][s] coalesced.
// ---------------------------------------------------------------------------
__global__ __launch_bounds__(256) void k_scores(
    const float* __restrict__ x, const float* __restrict__ Q,
    const float* __restrict__ wk, const float* __restrict__ msk,
    float* __restrict__ P)
{
    __shared__ float Kl[81 * 132];
    __shared__ float sc[21 * 85];
    __shared__ float rsum[24];
    const int tid = threadIdx.x;
    const int tq = blockIdx.x, h = blockIdx.y, b = blockIdx.z;
    const int t0g = tq * 21;
    const int nt = (tq == 3) ? 18 : 21;

    {
        const float* wkb = wk + (size_t)h * Dq;
        for (int idx = tid; idx < Tq * 32; idx += 256) {
            const int r = idx >> 5, c = idx & 31;
            const float4 xv = *(const float4*)(x + (size_t)(b * Tq + r) * Dq + c * 4);
            const float4 wv = *(const float4*)(wkb + c * 4);
            float4 kv;
            kv.x = xv.x * wv.x; kv.y = xv.y * wv.y;
            kv.z = xv.z * wv.z; kv.w = xv.w * wv.w;
            *(float4*)(&Kl[r * 132 + c * 4]) = kv;
        }
    }
    __syncthreads();

    if (tid < 252) {
        const int tg = tid / 12, sg = tid % 12;
        const int t = imin(t0g + tg, Tq - 1);
        const float* qrow = Q + ((size_t)(b * Tq + t) * Hq + h) * Dq;

        int sidx[7];
        #pragma unroll
        for (int j = 0; j < 7; ++j) sidx[j] = imin(sg + 12 * j, Tq - 1);

        float acc[7];
        #pragma unroll
        for (int j = 0; j < 7; ++j) acc[j] = 0.f;

        #pragma unroll 4
        for (int k4 = 0; k4 < 32; ++k4) {
            const float4 qv = *(const float4*)(qrow + k4 * 4);
            #pragma unroll
            for (int j = 0; j < 7; ++j) {
                const float4 kv = *(const float4*)(&Kl[sidx[j] * 132 + k4 * 4]);
                acc[j] += l1_4(qv, kv);
            }
        }
        const float ns = -0.08838834764831845f;   // -1/sqrt(128)
        #pragma unroll
        for (int j = 0; j < 7; ++j)
            sc[tg * 85 + sg + 12 * j] = acc[j] * ns;
    }
    __syncthreads();

    {
        const int w = tid >> 6, lane = tid & 63;
        for (int r = w; r < nt; r += 4) {
            float* row = sc + r * 85;
            const bool hi = (lane + 64) < Tq;
            const float v0 = row[lane];
            const float v1 = hi ? row[lane + 64] : -1e30f;
            float m = fmaxf(v0, v1);
            #pragma unroll
            for (int off = 32; off > 0; off >>= 1)
                m = fmaxf(m, __shfl_xor(m, off));
            const float e0 = __expf(v0 - m);
            const float e1 = hi ? __expf(v1 - m) : 0.f;
            float s = e0 + e1;
            #pragma unroll
            for (int off = 32; off > 0; off >>= 1)
                s += __shfl_xor(s, off);
            row[lane] = e0;
            if (hi) row[lane + 64] = e1;
            if (lane == 0) rsum[r] = 1.0f / s;
        }
    }
    __syncthreads();

    for (int idx = tid; idx < nt * Tq; idx += 256) {
        const int tl = idx / Tq, s = idx - tl * Tq;
        const int tg2 = t0g + tl;
        const float mv = msk[((size_t)h * Tq + tg2) * Tq + s];
        const float pm = sc[tl * 85 + s] * rsum[tl] * mv;
        P[(((size_t)b * Tq + tg2) * Hq + h) * PS + s] = pm;
    }
}

// ---------------------------------------------------------------------------
// K2b: ap output. grid (81) = t, block 256. ap[t][s][h] = P[0][t][h][s]-1+msk.
// ---------------------------------------------------------------------------
__global__ __launch_bounds__(256) void k_ap(
    const float* __restrict__ P, const float* __restrict__ msk,
    float* __restrict__ out)
{
    const int t = blockIdx.x;
    const float* Pt = P + ((size_t)t * Hq) * PS;
    float* apb = out + BTD + (size_t)t * Tq * Hq;
    for (int idx = threadIdx.x; idx < Tq * Hq; idx += 256) {
        const int h = idx & 7, s = idx >> 3;
        const float mv = msk[((size_t)h * Tq + t) * Tq + s];
        apb[(size_t)s * Hq + h] = Pt[(size_t)h * PS + s] - 1.0f + mv;
    }
}

// ---------------------------------------------------------------------------
// K3: bo einsum + quick-gelu + fanout + residual. grid (21, 16) = (t-chunk4, b),
// block 256 = 4 waves. P tile [4t][8h][84s] staged contiguously. Wave w sums
// heads {2w,2w+1} for 4 t; lanes = d/2, s blocked by 4 (b128 P reads).
// LDS reduce -> gelu -> fanout (2 t per thread, fw row reused).
// ---------------------------------------------------------------------------
__global__ __launch_bounds__(256) void k_out(
    const float* __restrict__ x, const float* __restrict__ P,
    const float* __restrict__ V, const float* __restrict__ fw,
    const float* __restrict__ fb, float* __restrict__ out)
{
    __shared__ float Pl[4][Hq][PS];
    __shared__ float bo_part[4][4][128];
    __shared__ float zs[4][128];
    const int tid = threadIdx.x;
    const int t0 = blockIdx.x * 4, b = blockIdx.y;

    // stage P tile: 2688 contiguous floats (t0=80 block over-reads into Q
    // region — finite values, results masked at store)
    {
        const float4* src = (const float4*)(P + ((size_t)b * Tq + t0) * Hq * PS);
        #pragma unroll
        for (int idx = tid; idx < 4 * Hq * PS / 4; idx += 256)
            ((float4*)Pl)[idx] = src[idx];
    }
    __syncthreads();

    const int w = tid >> 6, lane = tid & 63;
    {
        const int d0 = lane * 2;
        const int h0 = w * 2, h1 = h0 + 1;
        float2 acc[4];
        #pragma unroll
        for (int i = 0; i < 4; ++i) acc[i] = make_float2(0.f, 0.f);
        const float* v0p = V + ((size_t)(b * Tq) * Hq + h0) * Dq + d0;
        const float* v1p = V + ((size_t)(b * Tq) * Hq + h1) * Dq + d0;
        for (int s4 = 0; s4 < 20; ++s4) {
            float4 p0[4], p1[4];
            #pragma unroll
            for (int t = 0; t < 4; ++t) {
                p0[t] = *(const float4*)(&Pl[t][h0][s4 * 4]);
                p1[t] = *(const float4*)(&Pl[t][h1][s4 * 4]);
            }
            #pragma unroll
            for (int ss = 0; ss < 4; ++ss) {
                const int s = s4 * 4 + ss;
                const float2 v0 = *(const float2*)(v0p + (size_t)s * Hq * Dq);
                const float2 v1 = *(const float2*)(v1p + (size_t)s * Hq * Dq);
                #pragma unroll
                for (int t = 0; t < 4; ++t) {
                    const float a0 = ((const float*)&p0[t])[ss];
                    const float a1 = ((const float*)&p1[t])[ss];
                    acc[t].x += a0 * v0.x + a1 * v1.x;
                    acc[t].y += a0 * v0.y + a1 * v1.y;
                }
            }
        }
        {   // tail s = 80
            const float2 v0 = *(const float2*)(v0p + (size_t)80 * Hq * Dq);
            const float2 v1 = *(const float2*)(v1p + (size_t)80 * Hq * Dq);
            #pragma unroll
            for (int t = 0; t < 4; ++t) {
                const float a0 = Pl[t][h0][80], a1 = Pl[t][h1][80];
                acc[t].x += a0 * v0.x + a1 * v1.x;
                acc[t].y += a0 * v0.y + a1 * v1.y;
            }
        }
        #pragma unroll
        for (int t = 0; t < 4; ++t) {
            bo_part[w][t][d0]     = acc[t].x;
            bo_part[w][t][d0 + 1] = acc[t].y;
        }
    }
    __syncthreads();

    #pragma unroll
    for (int idx = tid; idx < 512; idx += 256) {   // gelu: 4t x 128d
        const int t = idx >> 7, d = idx & 127;
        const float bo = bo_part[0][t][d] + bo_part[1][t][d]
                       + bo_part[2][t][d] + bo_part[3][t][d];
        const float tt = bo + 4.0f;
        const float sg = 1.0f / (1.0f + __expf(-1.702f * tt));
        zs[t][d] = tt * sg - 4.0f;
    }
    __syncthreads();

    {   // fanout: each thread does (t, n) and (t+2, n); fw row n reused
        const int n = tid & 127;
        const float* fwr = fw + (size_t)n * Dq;
        const float fbn = fb[n];
        #pragma unroll
        for (int i = 0; i < 2; ++i) {
            const int t = (tid >> 7) + 2 * i;
            float a = 0.f;
            #pragma unroll 8
            for (int k4 = 0; k4 < 32; ++k4) {
                const float4 z4 = *(const float4*)(&zs[t][k4 * 4]);
                const float4 w4 = *(const float4*)(fwr + k4 * 4);
                a += z4.x * w4.x + z4.y * w4.y + z4.z * w4.z + z4.w * w4.w;
            }
            const int tg2 = t0 + t;
            if (tg2 < Tq) {
                const size_t o = ((size_t)b * Tq + tg2) * Dq + n;
                out[o] = x[o] + a + fbn;
            }
        }
    }
}

extern "C" void kernel_launch(void* const* d_in, const int* in_sizes, int n_in,
                              void* d_out, int out_size, void* d_ws, size_t ws_size,
                              hipStream_t stream) {
    const float* x        = (const float*)d_in[0];
    const float* msk      = (const float*)d_in[1];
    const float* wqkv_w   = (const float*)d_in[2];
    const float* wqkv_b   = (const float*)d_in[3];
    const float* wk_w     = (const float*)d_in[4];
    const float* fanout_w = (const float*)d_in[5];
    const float* fanout_b = (const float*)d_in[6];
    const float* he       = (const float*)d_in[7];
    float* out = (float*)d_out;
    float* ws  = (float*)d_ws;

    float* P   = ws + P_OFF;
    float* Q   = ws + Q_OFF;
    float* V   = ws + V_OFF;
    unsigned short* xb = (unsigned short*)(ws + XB_OFF);
    unsigned short* Wb = (unsigned short*)(ws + WB_OFF);

    k_prep<<<dim3(418), 256, 0, stream>>>(wqkv_w, x, Wb, xb);
    k_qkv_mfma<<<dim3(21, 32), 256, 0, stream>>>(xb, Wb, wqkv_b, he, Q, V);
    k_scores<<<dim3(4, 8, 16), 256, 0, stream>>>(x, Q, wk_w, msk, P);
    k_ap<<<dim3(81), 256, 0, stream>>>(P, msk, out);
    k_out<<<dim3(21, 16), 256, 0, stream>>>(x, P, V, fanout_w, fanout_b, out);
}

// Round 6
// 130.745 us; speedup vs baseline: 1.3817x; 1.0590x over previous
//
#include <hip/hip_runtime.h>
#include <math.h>

#define Bq 16
#define Tq 81
#define Dq 128
#define Hq 8
#define BT (Bq*Tq)          // 1296
#define BTD (Bq*Tq*Dq)      // 165888 (out region 0)
#define PS 84               // padded s-stride of P
// ws layout (floats). P: [b][t][h][s(pad 84)]
#define P_SZ   (Bq*Tq*Hq*PS)        // 870912
#define QV_SZ  (BT*Hq*Dq)           // 1327104
#define P_OFF  0
#define Q_OFF  (P_OFF + P_SZ)
#define V_OFF  (Q_OFF + QV_SZ)
#define XB_OFF (V_OFF + QV_SZ)      // xb: 1296x128 bf16 (ushort)
#define XB_FSZ (BTD/2)
#define WB_OFF (XB_OFF + XB_FSZ)    // Wb: 2048x128 bf16

typedef __attribute__((ext_vector_type(8))) short short8;
typedef __attribute__((ext_vector_type(4))) float f32x4;

__device__ __forceinline__ float l1_4(const float4 q, const float4 k) {
    return fabsf(q.x - k.x) + fabsf(q.y - k.y) + fabsf(q.z - k.z) + fabsf(q.w - k.w);
}
__device__ __forceinline__ int imin(int a, int b) { return a < b ? a : b; }
__device__ __forceinline__ unsigned short f2bf(float f) {   // RNE f32 -> bf16
    unsigned u = __float_as_uint(f);
    u += 0x7fffu + ((u >> 16) & 1u);
    return (unsigned short)(u >> 16);
}

// ---------------------------------------------------------------------------
// K0: convert wqkv_w and x to bf16 row-major. grid 418 x 256.
// ---------------------------------------------------------------------------
__global__ __launch_bounds__(256) void k_prep(
    const float* __restrict__ w, const float* __restrict__ x,
    unsigned short* __restrict__ Wb, unsigned short* __restrict__ xb)
{
    const int NW4 = (Hq * 2 * Dq * Dq) / 4;   // 65536
    const int NX4 = BTD / 4;                  // 41472
    const int idx = blockIdx.x * 256 + threadIdx.x;
    if (idx < NW4) {
        const float4 v = ((const float4*)w)[idx];
        ushort4 o;
        o.x = f2bf(v.x); o.y = f2bf(v.y); o.z = f2bf(v.z); o.w = f2bf(v.w);
        ((ushort4*)Wb)[idx] = o;
    } else if (idx < NW4 + NX4) {
        const int j = idx - NW4;
        const float4 v = ((const float4*)x)[j];
        ushort4 o;
        o.x = f2bf(v.x); o.y = f2bf(v.y); o.z = f2bf(v.z); o.w = f2bf(v.w);
        ((ushort4*)xb)[j] = o;
    }
}

// ---------------------------------------------------------------------------
// K1: QKV GEMM via bf16 MFMA 16x16x32. grid (21, 32), 256 thr = 4 waves.
// Wave w: m-tile mt = bx*4+w (16 rows), n-range n0 = by*64 (4 n-tiles).
// C/D map: col=lane&15, row=quad*4+reg. Epilogue +bias, *he for V, stores
// Q/V in [b][h][t][d] layout (contiguous per-(b,h) slabs for K2/K3).
// ---------------------------------------------------------------------------
__global__ __launch_bounds__(256) void k_qkv_mfma(
    const unsigned short* __restrict__ xb, const unsigned short* __restrict__ Wb,
    const float* __restrict__ bias, const float* __restrict__ he,
    float* __restrict__ Qo, float* __restrict__ Vo)
{
    const int tid = threadIdx.x;
    const int w = tid >> 6, lane = tid & 63;
    const int ln = lane & 15, quad = lane >> 4;
    const int mt = blockIdx.x * 4 + w;            // 0..83; 81..83 tail pads
    const int n0 = blockIdx.y * 64;
    const int h  = blockIdx.y >> 2;
    const int isV = (blockIdx.y >> 1) & 1;
    const int c0 = (blockIdx.y & 1) * 64;

    const int row = mt * 16 + ln;
    const int arow = row < BT ? row : BT - 1;
    const unsigned short* xa  = xb + (size_t)arow * Dq + quad * 8;
    const unsigned short* wb0 = Wb + (size_t)(n0 + ln) * Dq + quad * 8;

    f32x4 acc[4];
    #pragma unroll
    for (int i = 0; i < 4; ++i) acc[i] = (f32x4){0.f, 0.f, 0.f, 0.f};

    #pragma unroll
    for (int kb = 0; kb < Dq; kb += 32) {
        const short8 af = *(const short8*)(xa + kb);
        #pragma unroll
        for (int nt = 0; nt < 4; ++nt) {
            const short8 bf = *(const short8*)(wb0 + (size_t)(nt * 16) * Dq + kb);
            acc[nt] = __builtin_amdgcn_mfma_f32_16x16x32_bf16(af, bf, acc[nt], 0, 0, 0);
        }
    }

    if (mt >= 81) return;
    const float scale = isV ? he[h] : 1.0f;
    float* dst = isV ? Vo : Qo;
    const int gm0 = mt * 16 + quad * 4;           // <= 1292
    #pragma unroll
    for (int nt = 0; nt < 4; ++nt) {
        const float bn = bias[n0 + nt * 16 + ln];
        #pragma unroll
        for (int r = 0; r < 4; ++r) {
            const int gm = gm0 + r;
            const int bb = gm / 81, tt = gm - bb * 81;
            dst[(((size_t)bb * Hq + h) * Tq + tt) * Dq + c0 + nt * 16 + ln] =
                (acc[nt][r] + bn) * scale;
        }
    }
}

// ---------------------------------------------------------------------------
// K2: scores + softmax + P (+ap for b==0). grid (4, 8, 16) = (tq, h, b),
// block 256. K = x*wk in LDS (81x132, conflict-free). Compute: 147 threads =
// 7 tg (3t) x 21 sg (4s strided by 21) -> 10.7 LDS-b128 per (t,s) pair.
// Q read from contiguous [b][h][t][d] slab. Wave-parallel softmax.
// P store [b][t][h][s] coalesced; ap fused for b==0.
// ---------------------------------------------------------------------------
__global__ __launch_bounds__(256) void k_scores(
    const float* __restrict__ x, const float* __restrict__ Q,
    const float* __restrict__ wk, const float* __restrict__ msk,
    float* __restrict__ P, float* __restrict__ out)
{
    __shared__ float Kl[81 * 132];
    __shared__ float sc[21 * 85];
    __shared__ float rsum[24];
    const int tid = threadIdx.x;
    const int tq = blockIdx.x, h = blockIdx.y, b = blockIdx.z;
    const int t0g = tq * 21;
    const int nt = (tq == 3) ? 18 : 21;

    // stage K = x * wk[h]  (81 rows x 128, row stride 132)
    {
        const float* wkb = wk + (size_t)h * Dq;
        for (int idx = tid; idx < Tq * 32; idx += 256) {
            const int r = idx >> 5, c = idx & 31;
            const float4 xv = *(const float4*)(x + (size_t)(b * Tq + r) * Dq + c * 4);
            const float4 wv = *(const float4*)(wkb + c * 4);
            float4 kv;
            kv.x = xv.x * wv.x; kv.y = xv.y * wv.y;
            kv.z = xv.z * wv.z; kv.w = xv.w * wv.w;
            *(float4*)(&Kl[r * 132 + c * 4]) = kv;
        }
    }
    __syncthreads();

    if (tid < 147) {
        const int tg = tid / 21, sg = tid % 21;   // tg 0..6
        const float* qrow[3];
        #pragma unroll
        for (int i = 0; i < 3; ++i) {
            const int t = imin(t0g + tg * 3 + i, Tq - 1);
            qrow[i] = Q + (((size_t)b * Hq + h) * Tq + t) * Dq;
        }
        int sidx[4];
        #pragma unroll
        for (int j = 0; j < 4; ++j) sidx[j] = imin(sg + 21 * j, Tq - 1);

        float acc[3][4];
        #pragma unroll
        for (int i = 0; i < 3; ++i)
            #pragma unroll
            for (int j = 0; j < 4; ++j) acc[i][j] = 0.f;

        #pragma unroll 2
        for (int k4 = 0; k4 < 32; ++k4) {
            float4 kv[4];
            #pragma unroll
            for (int j = 0; j < 4; ++j)
                kv[j] = *(const float4*)(&Kl[sidx[j] * 132 + k4 * 4]);
            #pragma unroll
            for (int i = 0; i < 3; ++i) {
                const float4 qv = *(const float4*)(qrow[i] + k4 * 4);
                #pragma unroll
                for (int j = 0; j < 4; ++j)
                    acc[i][j] += l1_4(qv, kv[j]);
            }
        }
        const float ns = -0.08838834764831845f;   // -1/sqrt(128)
        #pragma unroll
        for (int i = 0; i < 3; ++i) {
            const int tl = tg * 3 + i;            // 0..20
            #pragma unroll
            for (int j = 0; j < 4; ++j)
                sc[tl * 85 + sg + 21 * j] = acc[i][j] * ns;
        }
    }
    __syncthreads();

    // wave-parallel softmax: wave w handles rows w, w+4, ...
    {
        const int w = tid >> 6, lane = tid & 63;
        for (int r = w; r < nt; r += 4) {
            float* row = sc + r * 85;
            const bool hi = (lane + 64) < Tq;
            const float v0 = row[lane];
            const float v1 = hi ? row[lane + 64] : -1e30f;
            float m = fmaxf(v0, v1);
            #pragma unroll
            for (int off = 32; off > 0; off >>= 1)
                m = fmaxf(m, __shfl_xor(m, off));
            const float e0 = __expf(v0 - m);
            const float e1 = hi ? __expf(v1 - m) : 0.f;
            float s = e0 + e1;
            #pragma unroll
            for (int off = 32; off > 0; off >>= 1)
                s += __shfl_xor(s, off);
            row[lane] = e0;
            if (hi) row[lane + 64] = e1;
            if (lane == 0) rsum[r] = 1.0f / s;
        }
    }
    __syncthreads();

    // store P[b][t][h][s] (coalesced s-runs) + fused ap for b==0
    const bool doap = (b == 0);
    for (int idx = tid; idx < nt * Tq; idx += 256) {
        const int tl = idx / Tq, s = idx - tl * Tq;
        const int tg2 = t0g + tl;
        const float mv = msk[((size_t)h * Tq + tg2) * Tq + s];
        const float pm = sc[tl * 85 + s] * rsum[tl] * mv;
        P[(((size_t)b * Tq + tg2) * Hq + h) * PS + s] = pm;
        if (doap) out[BTD + ((size_t)tg2 * Tq + s) * Hq + h] = pm - 1.0f + mv;
    }
}

// ---------------------------------------------------------------------------
// K3: bo einsum + quick-gelu + fanout + residual. grid (11, 16) = (t-chunk8, b),
// block 512 = 8 waves; wave w = head w, lanes = d/2 (one wave V read = one
// contiguous 512B row, V layout [b][h][s][d]). P tile [8t][8h][84s] staged
// contiguously; s blocked by 4 (b128 broadcast reads). 8-way LDS reduce ->
// gelu -> fanout (fw row loaded once per k4, reused across the thread's 2 t).
// ---------------------------------------------------------------------------
__global__ __launch_bounds__(512) void k_out(
    const float* __restrict__ x, const float* __restrict__ P,
    const float* __restrict__ V, const float* __restrict__ fw,
    const float* __restrict__ fb, float* __restrict__ out)
{
    __shared__ float Pl[8][Hq][PS];          // 21.5 KB
    __shared__ float bo_part[8][8][128];     // 32 KB
    __shared__ float zs[8][128];             // 4 KB
    const int tid = threadIdx.x;
    const int t0 = blockIdx.x * 8, b = blockIdx.y;

    // stage P tile: 5376 contiguous floats (last block over-reads into Q
    // region — finite, masked at store)
    {
        const float4* src = (const float4*)(P + ((size_t)b * Tq + t0) * Hq * PS);
        #pragma unroll
        for (int idx = tid; idx < 8 * Hq * PS / 4; idx += 512)
            ((float4*)Pl)[idx] = src[idx];
    }
    __syncthreads();

    const int w = tid >> 6, lane = tid & 63;   // w = head
    {
        const int d0 = lane * 2;
        float2 acc[8];
        #pragma unroll
        for (int i = 0; i < 8; ++i) acc[i] = make_float2(0.f, 0.f);
        const float* vp = V + (((size_t)b * Hq + w) * Tq) * Dq + d0;
        for (int s4 = 0; s4 < 20; ++s4) {
            float4 p[8];
            #pragma unroll
            for (int t = 0; t < 8; ++t)
                p[t] = *(const float4*)(&Pl[t][w][s4 * 4]);
            #pragma unroll
            for (int ss = 0; ss < 4; ++ss) {
                const int s = s4 * 4 + ss;
                const float2 vv = *(const float2*)(vp + (size_t)s * Dq);
                #pragma unroll
                for (int t = 0; t < 8; ++t) {
                    const float pv = ((const float*)&p[t])[ss];
                    acc[t].x = fmaf(pv, vv.x, acc[t].x);
                    acc[t].y = fmaf(pv, vv.y, acc[t].y);
                }
            }
        }
        {   // tail s = 80
            const float2 vv = *(const float2*)(vp + (size_t)80 * Dq);
            #pragma unroll
            for (int t = 0; t < 8; ++t) {
                const float pv = Pl[t][w][80];
                acc[t].x = fmaf(pv, vv.x, acc[t].x);
                acc[t].y = fmaf(pv, vv.y, acc[t].y);
            }
        }
        #pragma unroll
        for (int t = 0; t < 8; ++t) {
            bo_part[w][t][d0]     = acc[t].x;
            bo_part[w][t][d0 + 1] = acc[t].y;
        }
    }
    __syncthreads();

    #pragma unroll
    for (int idx = tid; idx < 1024; idx += 512) {   // gelu: 8t x 128d
        const int t = idx >> 7, d = idx & 127;
        float bo = 0.f;
        #pragma unroll
        for (int ww = 0; ww < 8; ++ww) bo += bo_part[ww][t][d];
        const float tt = bo + 4.0f;
        const float sg = 1.0f / (1.0f + __expf(-1.702f * tt));
        zs[t][d] = tt * sg - 4.0f;
    }
    __syncthreads();

    {   // fanout: thread -> (n = tid&127), t in {tg, tg+4}; fw row shared
        const int n = tid & 127, tg = tid >> 7;
        const float* fwr = fw + (size_t)n * Dq;
        const float fbn = fb[n];
        float a0 = 0.f, a1 = 0.f;
        #pragma unroll 8
        for (int k4 = 0; k4 < 32; ++k4) {
            const float4 w4 = *(const float4*)(fwr + k4 * 4);
            const float4 z0 = *(const float4*)(&zs[tg][k4 * 4]);
            const float4 z1 = *(const float4*)(&zs[tg + 4][k4 * 4]);
            a0 += z0.x * w4.x + z0.y * w4.y + z0.z * w4.z + z0.w * w4.w;
            a1 += z1.x * w4.x + z1.y * w4.y + z1.z * w4.z + z1.w * w4.w;
        }
        const int t1 = t0 + tg, t2 = t0 + tg + 4;
        if (t1 < Tq) {
            const size_t o = ((size_t)b * Tq + t1) * Dq + n;
            out[o] = x[o] + a0 + fbn;
        }
        if (t2 < Tq) {
            const size_t o = ((size_t)b * Tq + t2) * Dq + n;
            out[o] = x[o] + a1 + fbn;
        }
    }
}

extern "C" void kernel_launch(void* const* d_in, const int* in_sizes, int n_in,
                              void* d_out, int out_size, void* d_ws, size_t ws_size,
                              hipStream_t stream) {
    const float* x        = (const float*)d_in[0];
    const float* msk      = (const float*)d_in[1];
    const float* wqkv_w   = (const float*)d_in[2];
    const float* wqkv_b   = (const float*)d_in[3];
    const float* wk_w     = (const float*)d_in[4];
    const float* fanout_w = (const float*)d_in[5];
    const float* fanout_b = (const float*)d_in[6];
    const float* he       = (const float*)d_in[7];
    float* out = (float*)d_out;
    float* ws  = (float*)d_ws;

    float* P   = ws + P_OFF;
    float* Q   = ws + Q_OFF;
    float* V   = ws + V_OFF;
    unsigned short* xb = (unsigned short*)(ws + XB_OFF);
    unsigned short* Wb = (unsigned short*)(ws + WB_OFF);

    k_prep<<<dim3(418), 256, 0, stream>>>(wqkv_w, x, Wb, xb);
    k_qkv_mfma<<<dim3(21, 32), 256, 0, stream>>>(xb, Wb, wqkv_b, he, Q, V);
    k_scores<<<dim3(4, 8, 16), 256, 0, stream>>>(x, Q, wk_w, msk, P, out);
    k_out<<<dim3(11, 16), 512, 0, stream>>>(x, P, V, fanout_w, fanout_b, out);
}